// Round 7
// baseline (389.436 us; speedup 1.0000x reference)
//
#include <hip/hip_runtime.h>

// 2-layer LSTM (B=4096,T=512,D=16,H=50)+FC via single-wave MFMA.
// R13: ILP restructure. 256-thread blocks, 4 compute waves (1/SIMD), each
// wave owns 3-4 gt-tiles -> 3-4 independent MFMA chains + cell-pairs per
// phase fill dependency-stall with issue (R10 had 2 lockstep waves/SIMD,
// ~46% stall). No stager: waves self-load x global->reg ring (R11-verified).
// LDS = h only. Math = R10/R12 cell2p (accuracy-verified, no eo clamp).
// Tile split keeps pack2h pairs at adjacent permuted halves:
//   w0:(0,1),(2,3)  w1:(4,5)+6  w2:(8,9)+7  w3:(10,11)+12.

#define TSTEPS 512
#define DIN 16
#define HID 50
#define BPB 16

typedef _Float16 half8 __attribute__((ext_vector_type(8)));
typedef __fp16 fp16x2 __attribute__((ext_vector_type(2)));
typedef float f32x4 __attribute__((ext_vector_type(4)));
typedef float f32x2 __attribute__((ext_vector_type(2)));

#define MF(A, B, C) __builtin_amdgcn_mfma_f32_16x16x32_f16((A), (B), (C), 0, 0, 0)

// LDS: h double-buffered [2][16][144] per layer.
#define HBUF 2304
#define H0_O 0
#define H1_O 4608
#define SH_BYTES 9216

// Barrier WITHOUT vmcnt drain: LDS ordering only (x global loads stay in flight).
#define BAR() asm volatile("s_waitcnt lgkmcnt(0)\ns_barrier" ::: "memory")

#define NL2E  (-1.4426950408889634f)   // -log2(e): scale for gates i,f,o
#define P2L2E (2.8853900817779268f)    // +2*log2(e): scale for gate g

__device__ __forceinline__ unsigned pack2h(float a, float b) {
  union { fp16x2 h; unsigned u; } pk;
  pk.h = __builtin_amdgcn_cvt_pkrtz(a, b);
  return pk.u;
}

// Pair-fused LSTM cell on PRE-SCALED gates (two independent cells A,B).
// g[0]=-L2E*i g[1]=-L2E*f g[2]=+2L2E*g g[3]=-L2E*o. C = 2L2E*c.
// Accuracy-verified in R10/R12 (absmax 4.88e-4).
__device__ __forceinline__ f32x2 cell2p(const f32x4 gA, const f32x4 gB, f32x2& C) {
  f32x2 gi = {gA[0], gB[0]}, gf = {gA[1], gB[1]};
  f32x2 gg = {gA[2], gB[2]}, go = {gA[3], gB[3]};
  f32x2 ei, ef, eg, eo;
  ei[0] = __builtin_amdgcn_exp2f(gi[0]); ei[1] = __builtin_amdgcn_exp2f(gi[1]);
  ef[0] = __builtin_amdgcn_exp2f(gf[0]); ef[1] = __builtin_amdgcn_exp2f(gf[1]);
  eg[0] = __builtin_amdgcn_exp2f(gg[0]); eg[1] = __builtin_amdgcn_exp2f(gg[1]);
  eo[0] = __builtin_amdgcn_exp2f(go[0]); eo[1] = __builtin_amdgcn_exp2f(go[1]);
  const f32x2 one = {1.f, 1.f};
  const f32x2 c2 = {P2L2E, P2L2E};
  f32x2 a = one + ei, f = one + ef, b = one + eg;
  f32x2 ab = a * b;
  f32x2 f2 = ef * c2 + c2;                 // 2L2E * f
  f32x2 t = (eg - one) * f2 + C * ab;
  f32x2 p = f * ab;
  f32x2 rp;
  rp[0] = __builtin_amdgcn_rcpf(p[0]);
  rp[1] = __builtin_amdgcn_rcpf(p[1]);
  C = t * rp;
  f32x2 ec;
  ec[0] = __builtin_amdgcn_exp2f(fminf(C[0], 30.f));
  ec[1] = __builtin_amdgcn_exp2f(fminf(C[1], 30.f));
  f32x2 q = (one + eo) * (one + ec);
  float r2 = __builtin_amdgcn_rcpf(q[0] * q[1]);
  f32x2 h;
  h[0] = (ec[0] - 1.f) * (r2 * q[1]);
  h[1] = (ec[1] - 1.f) * (r2 * q[0]);
  return h;
}

// A-frag (fp16, 16x16x32): lane row g'=16gt+(lane&15)=4u+j, k-pos p=kt*32+(lane>>4)*8+i.
// permk: pos p holds source k = 8*(p>>3) + 4*(p&1) + ((p>>1)&3).
__device__ __forceinline__ half8 load_wfrag(const float* __restrict__ W, int kld,
                                            bool permk, int kreal, int gt, int kt,
                                            int lane, float scale) {
  const int gp = 16 * gt + (lane & 15);
  const int u = gp >> 2, j = gp & 3;
  const int kb = kt * 32 + (lane >> 4) * 8;
  half8 f;
#pragma unroll
  for (int i = 0; i < 8; ++i) {
    const int p = kb + i;
    const int kk = permk ? ((p & ~7) + (((p & 1) << 2) | ((p >> 1) & 3))) : p;
    float v = (u < HID && kk < kreal) ? W[(j * HID + u) * kld + kk] : 0.f;
    f[i] = (_Float16)(v * scale);
  }
  return f;
}

// x self-load (R11-verified): lane (bcol,kg) takes 8 floats from row bcol,
// offset (kg&1)*8; kg>=2 duplicates are multiplied by zero A-frag weights.
#define LOADX(R0, R1, TT)                                                      \
  do {                                                                         \
    int tl_ = (TT);                                                            \
    if (tl_ > TSTEPS - 1) tl_ = TSTEPS - 1;                                    \
    const float* p_ = xcol + (size_t)tl_ * DIN;                                \
    (R0) = *(const float4*)p_;                                                 \
    (R1) = *(const float4*)(p_ + 4);                                           \
  } while (0)

#define BXB(BX, R0, R1)                                                        \
  do {                                                                         \
    union { half8 h8; fp16x2 p2[4]; } u_;                                      \
    u_.p2[0] = __builtin_amdgcn_cvt_pkrtz((R0).x, (R0).y);                     \
    u_.p2[1] = __builtin_amdgcn_cvt_pkrtz((R0).z, (R0).w);                     \
    u_.p2[2] = __builtin_amdgcn_cvt_pkrtz((R1).x, (R1).y);                     \
    u_.p2[3] = __builtin_amdgcn_cvt_pkrtz((R1).z, (R1).w);                     \
    (BX) = u_.h8;                                                              \
  } while (0)

extern "C" __global__ void __launch_bounds__(256, 1)
lstm2_v13(const float* __restrict__ x,
          const float* __restrict__ Wih0, const float* __restrict__ Whh0,
          const float* __restrict__ bih0, const float* __restrict__ bhh0,
          const float* __restrict__ Wih1, const float* __restrict__ Whh1,
          const float* __restrict__ bih1, const float* __restrict__ bhh1,
          const float* __restrict__ Wfc, const float* __restrict__ bfc,
          float* __restrict__ out) {
  __shared__ __align__(16) char sh[SH_BYTES];
  const int tid = threadIdx.x;
  const int lane = tid & 63;
  const int wv = tid >> 6;            // 0..3
  const int bcol = lane & 15;
  const int kg = lane >> 4;
  const int bbase = blockIdx.x * BPB;

  // tile slots: [0,1] = pair (even base gA); wv0 also pair [2,3]=(2,3);
  // wv1-3: slot [2] = single gS.
  const int gA = (wv == 0) ? 0 : (wv == 1) ? 4 : (wv == 2) ? 8 : 10;
  const int gS = (wv == 1) ? 6 : (wv == 2) ? 7 : 12;  // unused for wv0

  const float* xcol = x + ((size_t)(bbase + bcol)) * TSTEPS * DIN + (kg & 1) * 8;

  for (int i = tid; i < SH_BYTES / 4; i += 256) ((int*)sh)[i] = 0;

  // ---- register-resident PRE-SCALED fp16 weight fragments + scaled f32 bias ----
  const float wsc = ((lane & 3) == 2) ? P2L2E : NL2E;
  half8 w0x[4], w0h[4][2], w1i[4][2], w1h[4][2];
  f32x4 bias0v[4] = {{0,0,0,0},{0,0,0,0},{0,0,0,0},{0,0,0,0}};
  f32x4 bias1v[4] = {{0,0,0,0},{0,0,0,0},{0,0,0,0},{0,0,0,0}};
  {
    int gts[4];
    gts[0] = gA; gts[1] = gA + 1;
    gts[2] = (wv == 0) ? 2 : gS;
    gts[3] = 3;  // wv0 only
    const int nslot = (wv == 0) ? 4 : 3;
#pragma unroll
    for (int si = 0; si < 4; ++si) {
      if (si < nslot) {
        const int gt = gts[si];
        w0x[si] = load_wfrag(Wih0, DIN, false, DIN, gt, 0, lane, wsc);
#pragma unroll
        for (int kt = 0; kt < 2; ++kt) {
          w0h[si][kt] = load_wfrag(Whh0, HID, true, HID, gt, kt, lane, wsc);
          w1i[si][kt] = load_wfrag(Wih1, HID, true, HID, gt, kt, lane, wsc);
          w1h[si][kt] = load_wfrag(Whh1, HID, true, HID, gt, kt, lane, wsc);
        }
        const int u = 4 * gt + kg;
        if (u < HID) {
#pragma unroll
          for (int j = 0; j < 4; ++j) {
            const float bs = (j == 2) ? P2L2E : NL2E;
            bias0v[si][j] = bs * (bih0[j * HID + u] + bhh0[j * HID + u]);
            bias1v[si][j] = bs * (bih1[j * HID + u] + bhh1[j * HID + u]);
          }
        }
      }
    }
  }

  // cell states: pair1 -> C0a(layer0),C1a(layer1); wv0 pair2 -> C0b,C1b;
  // wv1-3 single (layer-paired {c1,c0}) -> C0b.
  f32x2 C0a = {0.f, 0.f}, C1a = {0.f, 0.f}, C0b = {0.f, 0.f}, C1b = {0.f, 0.f};
  const int hoff = bcol * 144 + kg * 16;
  const int wo_p1 = bcol * 144 + (gA >> 1) * 16 + kg * 4;
  const int wo_p2 = bcol * 144 + 16 + kg * 4;  // wv0 pair2: m=1
  const int wo_s  = bcol * 144 + (8 * (gS >> 1) + 2 * kg + (gS & 1)) * 2;

  BAR();  // LDS zeroed

  // ---- prologue: h0[0] = cell(bias0 + Wih0 x[0]) -> h0 buf 0 ----
  float4 a0, a1, b0, b1;
  LOADX(a0, a1, 0);
  half8 bx0;
  BXB(bx0, a0, a1);
  LOADX(a0, a1, 1);  // ring A: x[1] for phase 0
  LOADX(b0, b1, 2);  // ring B: x[2] for phase 1
  {
    f32x4 r0 = MF(w0x[0], bx0, bias0v[0]);
    f32x4 r1 = MF(w0x[1], bx0, bias0v[1]);
    f32x2 H = cell2p(r0, r1, C0a);
    *(unsigned*)(sh + H0_O + wo_p1) = pack2h(H[0], H[1]);
    if (wv == 0) {
      f32x4 r2 = MF(w0x[2], bx0, bias0v[2]);
      f32x4 r3 = MF(w0x[3], bx0, bias0v[3]);
      f32x2 H2 = cell2p(r2, r3, C0b);
      *(unsigned*)(sh + H0_O + wo_p2) = pack2h(H2[0], H2[1]);
    } else {
      f32x4 rs = MF(w0x[2], bx0, bias0v[2]);
      f32x2 Ct = {0.f, 0.f};
      f32x2 Hs = cell2p(rs, rs, Ct);
      *(_Float16*)(sh + H0_O + wo_s) = (_Float16)Hs[0];
      C0b[0] = 0.f;     // c1 init
      C0b[1] = Ct[0];   // c0 from prologue
    }
  }
  BAR();

// layer1 gate chain for slot SI (4 MFMAs) and layer0 chain (3 MFMAs).
#define QCHAIN(QV, SI)                                                         \
  f32x4 QV = MF(w1i[SI][0], bh0[0], bias1v[SI]);                               \
  QV = MF(w1h[SI][0], bh1[0], QV);                                             \
  QV = MF(w1i[SI][1], bh0[1], QV);                                             \
  QV = MF(w1h[SI][1], bh1[1], QV)
#define RCHAIN(RV, SI, BX)                                                     \
  f32x4 RV = MF(w0x[SI], (BX), bias0v[SI]);                                    \
  RV = MF(w0h[SI][0], bh0[0], RV);                                             \
  RV = MF(w0h[SI][1], bh0[1], RV)

// one step at parity P (reads h bufs P, writes P^1) with register x-frag BX.
#define STEP(P, BX)                                                            \
  do {                                                                         \
    half8 bh0[2], bh1[2];                                                      \
    _Pragma("unroll") for (int kt = 0; kt < 2; ++kt) {                         \
      bh0[kt] = *(const half8*)(sh + H0_O + (P)*HBUF + hoff + kt * 64);        \
      bh1[kt] = *(const half8*)(sh + H1_O + (P)*HBUF + hoff + kt * 64);        \
    }                                                                          \
    RCHAIN(rv0, 0, BX);                                                        \
    RCHAIN(rv1, 1, BX);                                                        \
    QCHAIN(qv0, 0);                                                            \
    QCHAIN(qv1, 1);                                                            \
    if (wv == 0) {                                                             \
      RCHAIN(rv2, 2, BX);                                                      \
      RCHAIN(rv3, 3, BX);                                                      \
      QCHAIN(qv2, 2);                                                          \
      QCHAIN(qv3, 3);                                                          \
      f32x2 H0p = cell2p(rv0, rv1, C0a);                                       \
      *(unsigned*)(sh + H0_O + ((P) ^ 1) * HBUF + wo_p1) = pack2h(H0p[0], H0p[1]); \
      f32x2 H1p = cell2p(qv0, qv1, C1a);                                       \
      *(unsigned*)(sh + H1_O + ((P) ^ 1) * HBUF + wo_p1) = pack2h(H1p[0], H1p[1]); \
      f32x2 H0q = cell2p(rv2, rv3, C0b);                                       \
      *(unsigned*)(sh + H0_O + ((P) ^ 1) * HBUF + wo_p2) = pack2h(H0q[0], H0q[1]); \
      f32x2 H1q = cell2p(qv2, qv3, C1b);                                       \
      *(unsigned*)(sh + H1_O + ((P) ^ 1) * HBUF + wo_p2) = pack2h(H1q[0], H1q[1]); \
    } else {                                                                   \
      RCHAIN(rvs, 2, BX);                                                      \
      QCHAIN(qvs, 2);                                                          \
      f32x2 H0p = cell2p(rv0, rv1, C0a);                                       \
      *(unsigned*)(sh + H0_O + ((P) ^ 1) * HBUF + wo_p1) = pack2h(H0p[0], H0p[1]); \
      f32x2 H1p = cell2p(qv0, qv1, C1a);                                       \
      *(unsigned*)(sh + H1_O + ((P) ^ 1) * HBUF + wo_p1) = pack2h(H1p[0], H1p[1]); \
      f32x2 Hs = cell2p(qvs, rvs, C0b);                                        \
      *(_Float16*)(sh + H1_O + ((P) ^ 1) * HBUF + wo_s) = (_Float16)Hs[0];     \
      *(_Float16*)(sh + H0_O + ((P) ^ 1) * HBUF + wo_s) = (_Float16)Hs[1];     \
    }                                                                          \
  } while (0)

  for (int s = 0; s < TSTEPS; s += 2) {
    // phase s (P=0): uses x[s+1] (ring A); reload A <- x[s+3]
    {
      half8 bxA;
      BXB(bxA, a0, a1);
      LOADX(a0, a1, s + 3);
      STEP(0, bxA);
    }
    BAR();
    // phase s+1 (P=1): uses x[s+2] (ring B); reload B <- x[s+4]
    {
      half8 bxB;
      BXB(bxB, b0, b1);
      LOADX(b0, b1, s + 4);
      STEP(1, bxB);
    }
    BAR();
  }

  // ---- FC epilogue: h1[511] in buf 0; read through pi-permutation ----
  if (tid < BPB) {
    float acc = bfc[0];
#pragma unroll 10
    for (int u = 0; u < HID; ++u) {
      const int pp = (u & ~7) + 2 * (u & 3) + ((u >> 2) & 1);
      float h = (float)(*(const _Float16*)(sh + H1_O + tid * 144 + pp * 2));
      acc = fmaf(Wfc[u], h, acc);
    }
    out[bbase + tid] = acc;
  }
}

extern "C" void kernel_launch(void* const* d_in, const int* in_sizes, int n_in,
                              void* d_out, int out_size, void* d_ws, size_t ws_size,
                              hipStream_t stream) {
  (void)in_sizes; (void)n_in; (void)d_ws; (void)ws_size; (void)out_size;
  lstm2_v13<<<dim3(4096 / BPB), dim3(256), 0, stream>>>(
      (const float*)d_in[0], (const float*)d_in[1], (const float*)d_in[2],
      (const float*)d_in[3], (const float*)d_in[4], (const float*)d_in[5],
      (const float*)d_in[6], (const float*)d_in[7], (const float*)d_in[8],
      (const float*)d_in[9], (const float*)d_in[10], (float*)d_out);
}

// Round 8
// 332.536 us; speedup vs baseline: 1.1711x; 1.1711x over previous
//
#include <hip/hip_runtime.h>

// 2-layer LSTM (B=4096,T=512,D=16,H=50)+FC via single-wave MFMA.
// R14: wave-count experiment. R10's structure/math verbatim, but 13 tiles
// split over 13 ONE-TILE compute waves + 1 stager (896 thr, ~3.5 waves/SIMD
// vs R10's 2). Per-wave: 7 chained MFMA + 1 layer-paired cell2p (R11's
// verified NT1 path, b16 h-writes). Per-SIMD issue ~= R10 but 3-4
// independent waves now fill dependency stalls (R13 showed 1 wave/SIMD
// exposes them; R10's 2 waves = 54% busy). x ring/stager/barriers = R10.

#define TSTEPS 512
#define DIN 16
#define HID 50
#define BPB 16

typedef _Float16 half8 __attribute__((ext_vector_type(8)));
typedef _Float16 half4v __attribute__((ext_vector_type(4)));
typedef __fp16 fp16x2 __attribute__((ext_vector_type(2)));
typedef float f32x4 __attribute__((ext_vector_type(4)));
typedef float f32x2 __attribute__((ext_vector_type(2)));

#define MF(A, B, C) __builtin_amdgcn_mfma_f32_16x16x32_f16((A), (B), (C), 0, 0, 0)

// LDS: h double-buffered [2][16][144]; x 4-slot ring [4][16][80].
#define HBUF 2304
#define XBUF 1280
#define H0_O 0
#define H1_O 4608
#define X_O  9216
#define SH_BYTES (9216 + 4 * XBUF)   // 14336

// Barrier WITHOUT vmcnt drain: LDS ordering only (stager loads stay in flight).
#define BAR() asm volatile("s_waitcnt lgkmcnt(0)\ns_barrier" ::: "memory")

#define NL2E  (-1.4426950408889634f)   // -log2(e): scale for gates i,f,o
#define P2L2E (2.8853900817779268f)    // +2*log2(e): scale for gate g

// Pair-fused LSTM cell on PRE-SCALED gates (two independent cells A,B).
// g[0]=-L2E*i g[1]=-L2E*f g[2]=+2L2E*g g[3]=-L2E*o. C = 2L2E*c.
// Accuracy-verified R10/R11/R12 (absmax 4.88e-4).
__device__ __forceinline__ f32x2 cell2p(const f32x4 gA, const f32x4 gB, f32x2& C) {
  f32x2 gi = {gA[0], gB[0]}, gf = {gA[1], gB[1]};
  f32x2 gg = {gA[2], gB[2]}, go = {gA[3], gB[3]};
  f32x2 ei, ef, eg, eo;
  ei[0] = __builtin_amdgcn_exp2f(gi[0]); ei[1] = __builtin_amdgcn_exp2f(gi[1]);
  ef[0] = __builtin_amdgcn_exp2f(gf[0]); ef[1] = __builtin_amdgcn_exp2f(gf[1]);
  eg[0] = __builtin_amdgcn_exp2f(gg[0]); eg[1] = __builtin_amdgcn_exp2f(gg[1]);
  eo[0] = __builtin_amdgcn_exp2f(go[0]); eo[1] = __builtin_amdgcn_exp2f(go[1]);
  const f32x2 one = {1.f, 1.f};
  const f32x2 c2 = {P2L2E, P2L2E};
  f32x2 a = one + ei, f = one + ef, b = one + eg;
  f32x2 ab = a * b;
  f32x2 f2 = ef * c2 + c2;                 // 2L2E * f
  f32x2 t = (eg - one) * f2 + C * ab;
  f32x2 p = f * ab;
  f32x2 rp;
  rp[0] = __builtin_amdgcn_rcpf(p[0]);
  rp[1] = __builtin_amdgcn_rcpf(p[1]);
  C = t * rp;
  f32x2 ec;
  ec[0] = __builtin_amdgcn_exp2f(fminf(C[0], 30.f));
  ec[1] = __builtin_amdgcn_exp2f(fminf(C[1], 30.f));
  f32x2 q = (one + eo) * (one + ec);
  float r2 = __builtin_amdgcn_rcpf(q[0] * q[1]);
  f32x2 h;
  h[0] = (ec[0] - 1.f) * (r2 * q[1]);
  h[1] = (ec[1] - 1.f) * (r2 * q[0]);
  return h;
}

// A-frag (fp16, 16x16x32): lane row g'=16gt+(lane&15)=4u+j, k-pos p=kt*32+(lane>>4)*8+i.
// permk: pos p holds source k = 8*(p>>3) + 4*(p&1) + ((p>>1)&3).
__device__ __forceinline__ half8 load_wfrag(const float* __restrict__ W, int kld,
                                            bool permk, int kreal, int gt, int kt,
                                            int lane, float scale) {
  const int gp = 16 * gt + (lane & 15);
  const int u = gp >> 2, j = gp & 3;
  const int kb = kt * 32 + (lane >> 4) * 8;
  half8 f;
#pragma unroll
  for (int i = 0; i < 8; ++i) {
    const int p = kb + i;
    const int kk = permk ? ((p & ~7) + (((p & 1) << 2) | ((p >> 1) & 3))) : p;
    float v = (u < HID && kk < kreal) ? W[(j * HID + u) * kld + kk] : 0.f;
    f[i] = (_Float16)(v * scale);
  }
  return f;
}

extern "C" __global__ void __launch_bounds__(896, 1)
lstm2_v14(const float* __restrict__ x,
          const float* __restrict__ Wih0, const float* __restrict__ Whh0,
          const float* __restrict__ bih0, const float* __restrict__ bhh0,
          const float* __restrict__ Wih1, const float* __restrict__ Whh1,
          const float* __restrict__ bih1, const float* __restrict__ bhh1,
          const float* __restrict__ Wfc, const float* __restrict__ bfc,
          float* __restrict__ out) {
  __shared__ __align__(16) char sh[SH_BYTES];
  const int tid = threadIdx.x;
  const int lane = tid & 63;
  const int wv = tid >> 6;            // 0..13
  const int bcol = lane & 15;
  const int kg = lane >> 4;
  const int bbase = blockIdx.x * BPB;
  const bool comp = (wv < 13);
  const int gt = wv;                  // one tile per compute wave

  // x-staging mapping (wave 13): lane -> (batch row sbb, float-quad q)
  const int sbb = lane >> 2, q = lane & 3;
  const float* xrow = x + ((size_t)(bbase + sbb) * TSTEPS) * DIN + q * 4;

  for (int i = tid; i < SH_BYTES / 4; i += 896) ((int*)sh)[i] = 0;

  // ---- register-resident PRE-SCALED fp16 weight fragments + scaled f32 bias ----
  const float wsc = ((lane & 3) == 2) ? P2L2E : NL2E;
  half8 w0x, w0h[2], w1i[2], w1h[2];
  f32x4 bias0v = {0, 0, 0, 0}, bias1v = {0, 0, 0, 0};
  if (comp) {
    w0x = load_wfrag(Wih0, DIN, false, DIN, gt, 0, lane, wsc);
#pragma unroll
    for (int kt = 0; kt < 2; ++kt) {
      w0h[kt] = load_wfrag(Whh0, HID, true, HID, gt, kt, lane, wsc);
      w1i[kt] = load_wfrag(Wih1, HID, true, HID, gt, kt, lane, wsc);
      w1h[kt] = load_wfrag(Whh1, HID, true, HID, gt, kt, lane, wsc);
    }
    const int u = 4 * gt + kg;
    if (u < HID) {
#pragma unroll
      for (int j = 0; j < 4; ++j) {
        const float bs = (j == 2) ? P2L2E : NL2E;
        bias0v[j] = bs * (bih0[j * HID + u] + bhh0[j * HID + u]);
        bias1v[j] = bs * (bih1[j * HID + u] + bhh1[j * HID + u]);
      }
    }
  }

  // layer-paired cell state: C = {c1, c0} (R11 NT1 path).
  f32x2 C = {0.f, 0.f};
  const int hoff = bcol * 144 + kg * 16;
  const int xoff = bcol * 80 + kg * 16;
  // h halfword write offset: u = 4gt+kg at permuted pos 8*(gt>>1)+2*kg+(gt&1).
  const int wo_s = bcol * 144 + (8 * (gt >> 1) + 2 * kg + (gt & 1)) * 2;

  BAR();  // LDS zeroed

  // stage x[0..2] -> slots 0..2 (wave 13, direct)
  if (wv == 13) {
#pragma unroll
    for (int t = 0; t < 3; ++t) {
      float4 xq = *(const float4*)(xrow + (size_t)t * DIN);
      half4v h4;
#pragma unroll
      for (int i = 0; i < 4; ++i) h4[i] = (_Float16)((const float*)&xq)[i];
      *(half4v*)(sh + X_O + t * XBUF + sbb * 80 + q * 8) = h4;
    }
  }
  BAR();

  // prologue: h0[0] = cell(bias0 + Wih0 x[0]) -> h0 buf 0; prefetch x[1] to reg.
  float4 xrA, xrB;
  half8 bxc;
  if (comp) {
    half8 bx0 = *(const half8*)(sh + X_O + 0 * XBUF + xoff);
    bxc = *(const half8*)(sh + X_O + 1 * XBUF + xoff);
    f32x4 r0 = MF(w0x, bx0, bias0v);
    f32x2 Cp = {0.f, 0.f};
    f32x2 Hs = cell2p(r0, r0, Cp);
    *(_Float16*)(sh + H0_O + wo_s) = (_Float16)Hs[0];
    C[0] = 0.f;     // c1 init
    C[1] = Cp[0];   // c0 from prologue
  } else if (wv == 13) {  // issue the register ring: x[3], x[4]
    xrA = *(const float4*)(xrow + (size_t)3 * DIN);
    xrB = *(const float4*)(xrow + (size_t)4 * DIN);
  }
  BAR();

// one compute step at parity P (reads h bufs P, writes P^1), register x-frag
// bxc (= x[t+1]), prefetch next phase's x from ring slot XSN. Chained MFMA
// (R10-style); layer-paired cell; b16 h writes (R11 NT1, verified).
#define STEPC(P, XSN)                                                          \
  do {                                                                         \
    half8 bh0[2], bh1[2];                                                      \
    _Pragma("unroll") for (int kt = 0; kt < 2; ++kt) {                         \
      bh0[kt] = *(const half8*)(sh + H0_O + (P)*HBUF + hoff + kt * 64);        \
      bh1[kt] = *(const half8*)(sh + H1_O + (P)*HBUF + hoff + kt * 64);        \
    }                                                                          \
    half8 bxn = *(const half8*)(sh + X_O + (XSN)*XBUF + xoff);                 \
    f32x4 qv = MF(w1i[0], bh0[0], bias1v);                                     \
    qv = MF(w1h[0], bh1[0], qv);                                               \
    qv = MF(w1i[1], bh0[1], qv);                                               \
    qv = MF(w1h[1], bh1[1], qv);                                               \
    f32x4 rv = MF(w0x, bxc, bias0v);                                           \
    rv = MF(w0h[0], bh0[0], rv);                                               \
    rv = MF(w0h[1], bh0[1], rv);                                               \
    f32x2 Hs = cell2p(qv, rv, C);                                              \
    *(_Float16*)(sh + H1_O + ((P) ^ 1) * HBUF + wo_s) = (_Float16)Hs[0];       \
    *(_Float16*)(sh + H0_O + ((P) ^ 1) * HBUF + wo_s) = (_Float16)Hs[1];       \
    bxc = bxn;                                                                 \
  } while (0)

// wave 13: ds-write XR (holds x[t+3]) into literal SLOT=(t+3)&3, load x[t+5].
#define STEPX(T, SLOT, XR)                                                     \
  do {                                                                         \
    half4v h4;                                                                 \
    _Pragma("unroll") for (int i = 0; i < 4; ++i)                              \
        h4[i] = (_Float16)((const float*)&(XR))[i];                            \
    *(half4v*)(sh + X_O + (SLOT)*XBUF + sbb * 80 + q * 8) = h4;                \
    int tl = (T) + 5;                                                          \
    if (tl > TSTEPS - 1) tl = TSTEPS - 1;                                      \
    (XR) = *(const float4*)(xrow + (size_t)tl * DIN);                          \
  } while (0)

  for (int s = 0; s < TSTEPS; s += 4) {
    // phase s   (P=0): uses x[s+1] (bxc), prefetch slot 2 = x[s+2]
    if (comp) { STEPC(0, 2); } else if (wv == 13) { STEPX(s, 3, xrA); }
    BAR();
    // phase s+1 (P=1): uses x[s+2], prefetch slot 3 = x[s+3]
    if (comp) { STEPC(1, 3); } else if (wv == 13) { STEPX(s + 1, 0, xrB); }
    BAR();
    // phase s+2 (P=0): uses x[s+3], prefetch slot 0 = x[s+4]
    if (comp) { STEPC(0, 0); } else if (wv == 13) { STEPX(s + 2, 1, xrA); }
    BAR();
    // phase s+3 (P=1): uses x[s+4], prefetch slot 1 = x[s+5]
    if (comp) { STEPC(1, 1); } else if (wv == 13) { STEPX(s + 3, 2, xrB); }
    BAR();
  }

  // ---- FC epilogue: h1[511] in buf 0; read through pi-permutation ----
  if (tid < BPB) {
    float acc = bfc[0];
#pragma unroll 10
    for (int u = 0; u < HID; ++u) {
      const int pp = (u & ~7) + 2 * (u & 3) + ((u >> 2) & 1);
      float h = (float)(*(const _Float16*)(sh + H1_O + tid * 144 + pp * 2));
      acc = fmaf(Wfc[u], h, acc);
    }
    out[bbase + tid] = acc;
  }
}

extern "C" void kernel_launch(void* const* d_in, const int* in_sizes, int n_in,
                              void* d_out, int out_size, void* d_ws, size_t ws_size,
                              hipStream_t stream) {
  (void)in_sizes; (void)n_in; (void)d_ws; (void)ws_size; (void)out_size;
  lstm2_v14<<<dim3(4096 / BPB), dim3(896), 0, stream>>>(
      (const float*)d_in[0], (const float*)d_in[1], (const float*)d_in[2],
      (const float*)d_in[3], (const float*)d_in[4], (const float*)d_in[5],
      (const float*)d_in[6], (const float*)d_in[7], (const float*)d_in[8],
      (const float*)d_in[9], (const float*)d_in[10], (float*)d_out);
}

// Round 9
// 328.007 us; speedup vs baseline: 1.1873x; 1.0138x over previous
//
#include <hip/hip_runtime.h>

// 2-layer LSTM (B=4096,T=512,D=16,H=50)+FC via single-wave MFMA.
// R15 = R10 (best: 330.7us) + chain cuts:
// (1) x-MFMA software-pipelined across the barrier: rx = MF(w0x, x[t+1])
//     computed at END of phase t-1 (x is ring-resident, barrier-independent)
//     -> post-barrier rv chain is 2-deep; bxc copies gone.
// (2) layer-1 qv chain 4-deep -> two 2-deep halves + vector add.
// (3) eo clamp dropped (accuracy validated R11/R12).
// Everything else (stager wave, x ring, cell2p math, layouts, barriers,
// 4x unroll) byte-identical to R10. R12's read predication EXCLUDED
// (proven regression).

#define TSTEPS 512
#define DIN 16
#define HID 50
#define BPB 16

typedef _Float16 half8 __attribute__((ext_vector_type(8)));
typedef _Float16 half4v __attribute__((ext_vector_type(4)));
typedef __fp16 fp16x2 __attribute__((ext_vector_type(2)));
typedef float f32x4 __attribute__((ext_vector_type(4)));
typedef float f32x2 __attribute__((ext_vector_type(2)));

#define MF(A, B, C) __builtin_amdgcn_mfma_f32_16x16x32_f16((A), (B), (C), 0, 0, 0)

// LDS: h double-buffered [2][16][144]; x 4-slot ring [4][16][80].
#define HBUF 2304
#define XBUF 1280
#define H0_O 0
#define H1_O 4608
#define X_O  9216
#define SH_BYTES (9216 + 4 * XBUF)   // 14336

// Barrier WITHOUT vmcnt drain: LDS ordering only (stager loads stay in flight).
#define BAR() asm volatile("s_waitcnt lgkmcnt(0)\ns_barrier" ::: "memory")

#define NL2E  (-1.4426950408889634f)   // -log2(e): scale for gates i,f,o
#define P2L2E (2.8853900817779268f)    // +2*log2(e): scale for gate g

__device__ __forceinline__ unsigned pack2h(float a, float b) {
  union { fp16x2 h; unsigned u; } pk;
  pk.h = __builtin_amdgcn_cvt_pkrtz(a, b);
  return pk.u;
}

// Pair-fused LSTM cell on PRE-SCALED gates (two independent cells A,B).
// g[0]=-L2E*i g[1]=-L2E*f g[2]=+2L2E*g g[3]=-L2E*o. C = 2L2E*c.
// Accuracy-verified R10/R11/R12 (absmax 4.88e-4). No eo clamp (R11/R12-ok).
__device__ __forceinline__ f32x2 cell2p(const f32x4 gA, const f32x4 gB, f32x2& C) {
  f32x2 gi = {gA[0], gB[0]}, gf = {gA[1], gB[1]};
  f32x2 gg = {gA[2], gB[2]}, go = {gA[3], gB[3]};
  f32x2 ei, ef, eg, eo;
  ei[0] = __builtin_amdgcn_exp2f(gi[0]); ei[1] = __builtin_amdgcn_exp2f(gi[1]);
  ef[0] = __builtin_amdgcn_exp2f(gf[0]); ef[1] = __builtin_amdgcn_exp2f(gf[1]);
  eg[0] = __builtin_amdgcn_exp2f(gg[0]); eg[1] = __builtin_amdgcn_exp2f(gg[1]);
  eo[0] = __builtin_amdgcn_exp2f(go[0]); eo[1] = __builtin_amdgcn_exp2f(go[1]);
  const f32x2 one = {1.f, 1.f};
  const f32x2 c2 = {P2L2E, P2L2E};
  f32x2 a = one + ei, f = one + ef, b = one + eg;
  f32x2 ab = a * b;
  f32x2 f2 = ef * c2 + c2;                 // 2L2E * f
  f32x2 t = (eg - one) * f2 + C * ab;
  f32x2 p = f * ab;
  f32x2 rp;
  rp[0] = __builtin_amdgcn_rcpf(p[0]);
  rp[1] = __builtin_amdgcn_rcpf(p[1]);
  C = t * rp;
  f32x2 ec;
  ec[0] = __builtin_amdgcn_exp2f(fminf(C[0], 30.f));
  ec[1] = __builtin_amdgcn_exp2f(fminf(C[1], 30.f));
  f32x2 q = (one + eo) * (one + ec);
  float r2 = __builtin_amdgcn_rcpf(q[0] * q[1]);
  f32x2 h;
  h[0] = (ec[0] - 1.f) * (r2 * q[1]);
  h[1] = (ec[1] - 1.f) * (r2 * q[0]);
  return h;
}

// A-frag (fp16, 16x16x32): lane row g'=16gt+(lane&15)=4u+j, k-pos p=kt*32+(lane>>4)*8+i.
// permk: pos p holds source k = 8*(p>>3) + 4*(p&1) + ((p>>1)&3).
__device__ __forceinline__ half8 load_wfrag(const float* __restrict__ W, int kld,
                                            bool permk, int kreal, int gt, int kt,
                                            int lane, float scale) {
  const int gp = 16 * gt + (lane & 15);
  const int u = gp >> 2, j = gp & 3;
  const int kb = kt * 32 + (lane >> 4) * 8;
  half8 f;
#pragma unroll
  for (int i = 0; i < 8; ++i) {
    const int p = kb + i;
    const int kk = permk ? ((p & ~7) + (((p & 1) << 2) | ((p >> 1) & 3))) : p;
    float v = (u < HID && kk < kreal) ? W[(j * HID + u) * kld + kk] : 0.f;
    f[i] = (_Float16)(v * scale);
  }
  return f;
}

extern "C" __global__ void __launch_bounds__(512, 2)
lstm2_v15(const float* __restrict__ x,
          const float* __restrict__ Wih0, const float* __restrict__ Whh0,
          const float* __restrict__ bih0, const float* __restrict__ bhh0,
          const float* __restrict__ Wih1, const float* __restrict__ Whh1,
          const float* __restrict__ bih1, const float* __restrict__ bhh1,
          const float* __restrict__ Wfc, const float* __restrict__ bfc,
          float* __restrict__ out) {
  __shared__ __align__(16) char sh[SH_BYTES];
  const int tid = threadIdx.x;
  const int lane = tid & 63;
  const int wv = tid >> 6;
  const int bcol = lane & 15;
  const int kg = lane >> 4;
  const int bbase = blockIdx.x * BPB;
  const bool comp = (wv < 7);

  // x-staging mapping (wave 7): lane -> (batch row sbb, float-quad q)
  const int sbb = lane >> 2, q = lane & 3;
  const float* xrow = x + ((size_t)(bbase + sbb) * TSTEPS) * DIN + q * 4;

  for (int i = tid; i < SH_BYTES / 4; i += 512) ((int*)sh)[i] = 0;

  // ---- register-resident PRE-SCALED fp16 weight fragments + scaled f32 bias ----
  const float wsc = ((lane & 3) == 2) ? P2L2E : NL2E;
  half8 w0x[2], w0h[2][2], w1i[2][2], w1h[2][2];
  f32x4 bias0v[2] = {{0,0,0,0},{0,0,0,0}}, bias1v[2] = {{0,0,0,0},{0,0,0,0}};
  if (comp) {
#pragma unroll
    for (int gi = 0; gi < 2; ++gi) {
      const int gt = 2 * wv + gi;
      w0x[gi] = load_wfrag(Wih0, DIN, false, DIN, gt, 0, lane, wsc);
#pragma unroll
      for (int kt = 0; kt < 2; ++kt) {
        w0h[gi][kt] = load_wfrag(Whh0, HID, true, HID, gt, kt, lane, wsc);
        w1i[gi][kt] = load_wfrag(Wih1, HID, true, HID, gt, kt, lane, wsc);
        w1h[gi][kt] = load_wfrag(Whh1, HID, true, HID, gt, kt, lane, wsc);
      }
      const int u = 8 * wv + 4 * gi + kg;
      if (u < HID) {
#pragma unroll
        for (int j = 0; j < 4; ++j) {
          const float bs = (j == 2) ? P2L2E : NL2E;
          bias0v[gi][j] = bs * (bih0[j * HID + u] + bhh0[j * HID + u]);
          bias1v[gi][j] = bs * (bih1[j * HID + u] + bhh1[j * HID + u]);
        }
      }
    }
  }
  f32x2 C0 = {0.f, 0.f}, C1 = {0.f, 0.f};
  const int hoff = bcol * 144 + kg * 16;
  const int xoff = bcol * 80 + kg * 16;
  const int wo32 = bcol * 144 + wv * 16 + kg * 4;

  BAR();  // LDS zeroed

  // stage x[0..2] -> slots 0..2 (wave 7, direct)
  if (wv == 7) {
#pragma unroll
    for (int t = 0; t < 3; ++t) {
      float4 xq = *(const float4*)(xrow + (size_t)t * DIN);
      half4v h4;
#pragma unroll
      for (int i = 0; i < 4; ++i) h4[i] = (_Float16)((const float*)&xq)[i];
      *(half4v*)(sh + X_O + t * XBUF + sbb * 80 + q * 8) = h4;
    }
  }
  BAR();

  // prologue: h0[0] = cell(bias0 + Wih0 x[0]) -> h0 buf 0; pre-issue rx for
  // phase 0 (x[1]).
  float4 xrA, xrB;
  f32x4 rx0, rx1;
  if (comp) {
    half8 bx0 = *(const half8*)(sh + X_O + 0 * XBUF + xoff);
    half8 bx1 = *(const half8*)(sh + X_O + 1 * XBUF + xoff);
    f32x4 a0 = MF(w0x[0], bx0, bias0v[0]);
    f32x4 a1 = MF(w0x[1], bx0, bias0v[1]);
    f32x2 H0 = cell2p(a0, a1, C0);
    *(unsigned*)(sh + H0_O + wo32) = pack2h(H0[0], H0[1]);
    rx0 = MF(w0x[0], bx1, bias0v[0]);   // x-part of phase 0's layer-0 gates
    rx1 = MF(w0x[1], bx1, bias0v[1]);
  } else if (wv == 7) {  // issue the register ring: x[3], x[4]
    xrA = *(const float4*)(xrow + (size_t)3 * DIN);
    xrB = *(const float4*)(xrow + (size_t)4 * DIN);
  }
  BAR();

// one compute step at compile-time h-parity P (reads h bufs P, writes P^1).
// rx0/rx1 hold the x-part (computed last phase, pipelined across the barrier);
// this phase reads x[t+2] from ring slot XSN and issues next phase's rx at
// the end. qv = two 2-deep MFMA halves + add; rv = 2-deep on top of rx.
#define STEPCOMP(P, XSN)                                                       \
  do {                                                                         \
    half8 bh0[2], bh1[2];                                                      \
    _Pragma("unroll") for (int kt = 0; kt < 2; ++kt) {                         \
      bh0[kt] = *(const half8*)(sh + H0_O + (P)*HBUF + hoff + kt * 64);        \
      bh1[kt] = *(const half8*)(sh + H1_O + (P)*HBUF + hoff + kt * 64);        \
    }                                                                          \
    half8 bxn = *(const half8*)(sh + X_O + (XSN)*XBUF + xoff);                 \
    const f32x4 z = {0.f, 0.f, 0.f, 0.f};                                      \
    f32x4 rv0 = MF(w0h[0][0], bh0[0], rx0);                                    \
    rv0 = MF(w0h[0][1], bh0[1], rv0);                                          \
    f32x4 rv1 = MF(w0h[1][0], bh0[0], rx1);                                    \
    rv1 = MF(w0h[1][1], bh0[1], rv1);                                          \
    f32x4 qa0 = MF(w1i[0][0], bh0[0], bias1v[0]);                              \
    qa0 = MF(w1h[0][0], bh1[0], qa0);                                          \
    f32x4 qb0 = MF(w1i[0][1], bh0[1], z);                                      \
    qb0 = MF(w1h[0][1], bh1[1], qb0);                                          \
    f32x4 qv0 = qa0 + qb0;                                                     \
    f32x4 qa1 = MF(w1i[1][0], bh0[0], bias1v[1]);                              \
    qa1 = MF(w1h[1][0], bh1[0], qa1);                                          \
    f32x4 qb1 = MF(w1i[1][1], bh0[1], z);                                      \
    qb1 = MF(w1h[1][1], bh1[1], qb1);                                          \
    f32x4 qv1 = qa1 + qb1;                                                     \
    f32x2 H0 = cell2p(rv0, rv1, C0);                                           \
    *(unsigned*)(sh + H0_O + ((P) ^ 1) * HBUF + wo32) = pack2h(H0[0], H0[1]);  \
    f32x2 H1 = cell2p(qv0, qv1, C1);                                           \
    *(unsigned*)(sh + H1_O + ((P) ^ 1) * HBUF + wo32) = pack2h(H1[0], H1[1]);  \
    rx0 = MF(w0x[0], bxn, bias0v[0]);                                          \
    rx1 = MF(w0x[1], bxn, bias0v[1]);                                          \
  } while (0)

// wave 7: ds-write XR (holds x[t+3]) into literal SLOT=(t+3)&3, load x[t+5].
#define STEPX(T, SLOT, XR)                                                     \
  do {                                                                         \
    half4v h4;                                                                 \
    _Pragma("unroll") for (int i = 0; i < 4; ++i)                              \
        h4[i] = (_Float16)((const float*)&(XR))[i];                            \
    *(half4v*)(sh + X_O + (SLOT)*XBUF + sbb * 80 + q * 8) = h4;                \
    int tl = (T) + 5;                                                          \
    if (tl > TSTEPS - 1) tl = TSTEPS - 1;                                      \
    (XR) = *(const float4*)(xrow + (size_t)tl * DIN);                          \
  } while (0)

  for (int s = 0; s < TSTEPS; s += 4) {
    // phase s   (P=0): rv from rx (=x[s+1]); reads slot 2 = x[s+2] for next rx
    if (comp) { STEPCOMP(0, 2); } else if (wv == 7) { STEPX(s, 3, xrA); }
    BAR();
    // phase s+1 (P=1): reads slot 3 = x[s+3]
    if (comp) { STEPCOMP(1, 3); } else if (wv == 7) { STEPX(s + 1, 0, xrB); }
    BAR();
    // phase s+2 (P=0): reads slot 0 = x[s+4]
    if (comp) { STEPCOMP(0, 0); } else if (wv == 7) { STEPX(s + 2, 1, xrA); }
    BAR();
    // phase s+3 (P=1): reads slot 1 = x[s+5]
    if (comp) { STEPCOMP(1, 1); } else if (wv == 7) { STEPX(s + 3, 2, xrB); }
    BAR();
  }

  // ---- FC epilogue: h1[511] in buf 0; read through pi-permutation ----
  if (tid < BPB) {
    float acc = bfc[0];
#pragma unroll 10
    for (int u = 0; u < HID; ++u) {
      const int pp = (u & ~7) + 2 * (u & 3) + ((u >> 2) & 1);
      float h = (float)(*(const _Float16*)(sh + H1_O + tid * 144 + pp * 2));
      acc = fmaf(Wfc[u], h, acc);
    }
    out[bbase + tid] = acc;
  }
}

extern "C" void kernel_launch(void* const* d_in, const int* in_sizes, int n_in,
                              void* d_out, int out_size, void* d_ws, size_t ws_size,
                              hipStream_t stream) {
  (void)in_sizes; (void)n_in; (void)d_ws; (void)ws_size; (void)out_size;
  lstm2_v15<<<dim3(4096 / BPB), dim3(512), 0, stream>>>(
      (const float*)d_in[0], (const float*)d_in[1], (const float*)d_in[2],
      (const float*)d_in[3], (const float*)d_in[4], (const float*)d_in[5],
      (const float*)d_in[6], (const float*)d_in[7], (const float*)d_in[8],
      (const float*)d_in[9], (const float*)d_in[10], (float*)d_out);
}